// Round 1
// baseline (564.908 us; speedup 1.0000x reference)
//
#include <hip/hip_runtime.h>
#include <hip/hip_bf16.h>

#define NROWS 131072
#define DIM   512
#define NK    64

typedef __attribute__((ext_vector_type(4))) float f32x4;
typedef __attribute__((ext_vector_type(8))) short s16x8;

// pack two fp32 -> one dword of two bf16 (RNE), low half = first arg
static __device__ __forceinline__ unsigned pk2(float a, float b) {
    union { __hip_bfloat162 h; unsigned u; } cv;
    cv.h = __float22bfloat162_rn(make_float2(a, b));
    return cv.u;
}

// --- Kernel 1: L2-normalize clusters (fp32) -> bf16 codebook in ws; zero loss slot.
// 64 blocks x 64 threads: one wave per cluster row.
__global__ void prep_kernel(const float* __restrict__ cl,
                            unsigned* __restrict__ cb,    // [64][256] dwords = bf16[64][512]
                            float* __restrict__ loss_out) {
    const int k = blockIdx.x, t = threadIdx.x;
    const float4* rp = reinterpret_cast<const float4*>(cl + k * DIM);
    float4 f0 = rp[2 * t], f1 = rp[2 * t + 1];
    float ss = f0.x*f0.x + f0.y*f0.y + f0.z*f0.z + f0.w*f0.w
             + f1.x*f1.x + f1.y*f1.y + f1.z*f1.z + f1.w*f1.w;
#pragma unroll
    for (int m = 1; m < 64; m <<= 1) ss += __shfl_xor(ss, m, 64);
    const float rn = 1.0f / fmaxf(sqrtf(ss), 1e-12f);   // matches F.normalize eps
    uint4 o;
    o.x = pk2(f0.x * rn, f0.y * rn);
    o.y = pk2(f0.z * rn, f0.w * rn);
    o.z = pk2(f1.x * rn, f1.y * rn);
    o.w = pk2(f1.z * rn, f1.w * rn);
    reinterpret_cast<uint4*>(cb + (size_t)k * (DIM / 2))[t] = o;
    if (k == 0 && t == 0) *loss_out = 0.0f;
}

// --- Kernel 2: fused normalize-x / GEMM(MFMA) / softmax / loss.
// LDS: bf16 clusters [64][512], XOR-swizzled in 16B units -> conflict-free B reads.
// Per wave per group: 16 rows x 64 clusters, K-loop 16 chunks of 32.
__global__ __launch_bounds__(512, 4) void fused_kernel(
        const float* __restrict__ x,
        const unsigned* __restrict__ cb,
        const float* __restrict__ alphap,
        float* __restrict__ out) {                 // [0]=loss, [1..]=probs[N][64]
    __shared__ unsigned short lds[NK * DIM];       // 65536 B exactly

    // stage codebook: 4096 16B-units; unit c6 of row r stored at (c6 ^ (r&7))
    for (int u = threadIdx.x; u < NK * DIM / 8; u += blockDim.x) {
        const int r = u >> 6, c6 = u & 63;
        const uint4 v = reinterpret_cast<const uint4*>(cb)[u];
        *reinterpret_cast<uint4*>(&lds[r * DIM + ((c6 ^ (r & 7)) << 3)]) = v;
    }
    __syncthreads();

    const float alpha = alphap[0];
    const int lane = threadIdx.x & 63;
    const int n = lane & 15;            // A-row / B-col / C-col lane index
    const int q = lane >> 4;            // quad
    const int sw = n & 7;               // LDS unit swizzle for this lane's B rows
    const int gw = (int)((blockIdx.x * blockDim.x + threadIdx.x) >> 6);
    const int nw = (int)((gridDim.x * blockDim.x) >> 6);

    // per-c-tile LDS row bases (cluster index = c*16 + n)
    const unsigned short* b_base = &lds[n * DIM];

    float lossa = 0.0f;

    for (int g = gw; g < NROWS / 16; g += nw) {
        const int row0 = g << 4;
        const float* xp = x + (size_t)(row0 + n) * DIM + (q << 3);
        f32x4 a0 = {0.f,0.f,0.f,0.f}, a1 = {0.f,0.f,0.f,0.f};
        f32x4 a2 = {0.f,0.f,0.f,0.f}, a3 = {0.f,0.f,0.f,0.f};
        float ss = 0.0f;

#pragma unroll
        for (int t = 0; t < 16; t++) {
            const float4 f0 = *reinterpret_cast<const float4*>(xp + t * 32);
            const float4 f1 = *reinterpret_cast<const float4*>(xp + t * 32 + 4);
            ss += f0.x*f0.x + f0.y*f0.y + f0.z*f0.z + f0.w*f0.w
                + f1.x*f1.x + f1.y*f1.y + f1.z*f1.z + f1.w*f1.w;
            union { s16x8 v; unsigned u[4]; } A;
            A.u[0] = pk2(f0.x, f0.y); A.u[1] = pk2(f0.z, f0.w);
            A.u[2] = pk2(f1.x, f1.y); A.u[3] = pk2(f1.z, f1.w);
            const int off = (((t << 2) | q) ^ sw) << 3;   // swizzled 16B unit
            const s16x8 b0 = *reinterpret_cast<const s16x8*>(b_base + off);
            const s16x8 b1 = *reinterpret_cast<const s16x8*>(b_base + 16 * DIM + off);
            const s16x8 b2 = *reinterpret_cast<const s16x8*>(b_base + 32 * DIM + off);
            const s16x8 b3 = *reinterpret_cast<const s16x8*>(b_base + 48 * DIM + off);
            a0 = __builtin_amdgcn_mfma_f32_16x16x32_bf16(A.v, b0, a0, 0, 0, 0);
            a1 = __builtin_amdgcn_mfma_f32_16x16x32_bf16(A.v, b1, a1, 0, 0, 0);
            a2 = __builtin_amdgcn_mfma_f32_16x16x32_bf16(A.v, b2, a2, 0, 0, 0);
            a3 = __builtin_amdgcn_mfma_f32_16x16x32_bf16(A.v, b3, a3, 0, 0, 0);
        }

        // finish ||x_row||: lanes (q,n) hold partial of row n over k = {32t + q*8 + j}
        ss += __shfl_xor(ss, 16, 64);
        ss += __shfl_xor(ss, 32, 64);
        const float rnorm = 1.0f / fmaxf(sqrtf(ss), 1e-12f);

#pragma unroll
        for (int r = 0; r < 4; r++) {
            // C row = q*4 + r; its rnorm lives at lanes with (lane&15) == q*4+r
            const float rn = __shfl(rnorm, (q << 2) + r, 64);
            const float i0 = a0[r] * rn, i1 = a1[r] * rn, i2 = a2[r] * rn, i3 = a3[r] * rn;
            const float z0 = i0 * alpha, z1 = i1 * alpha, z2 = i2 * alpha, z3 = i3 * alpha;
            float mx = fmaxf(fmaxf(z0, z1), fmaxf(z2, z3));
#pragma unroll
            for (int m = 1; m < 16; m <<= 1) mx = fmaxf(mx, __shfl_xor(mx, m, 64));
            const float e0 = __expf(z0 - mx), e1 = __expf(z1 - mx);
            const float e2 = __expf(z2 - mx), e3 = __expf(z3 - mx);
            float s  = e0 + e1 + e2 + e3;
            float sl = e0 * i0 + e1 * i1 + e2 * i2 + e3 * i3;   // loss uses pre-alpha ip
#pragma unroll
            for (int m = 1; m < 16; m <<= 1) {
                s  += __shfl_xor(s,  m, 64);
                sl += __shfl_xor(sl, m, 64);
            }
            const float inv = 1.0f / s;
            float* pr = out + 1 + (size_t)(row0 + (q << 2) + r) * NK + n;
            pr[0]  = e0 * inv;
            pr[16] = e1 * inv;
            pr[32] = e2 * inv;
            pr[48] = e3 * inv;
            if (n == 0) lossa += sl * inv;      // one contribution per row
        }
    }

    // wave-level loss partials live in lanes 0,16,32,48
    lossa += __shfl_xor(lossa, 16, 64);
    lossa += __shfl_xor(lossa, 32, 64);
    if (lane == 0) atomicAdd(out, -lossa * (1.0f / NROWS));
}

extern "C" void kernel_launch(void* const* d_in, const int* in_sizes, int n_in,
                              void* d_out, int out_size, void* d_ws, size_t ws_size,
                              hipStream_t stream) {
    const float* x  = (const float*)d_in[0];
    const float* cl = (const float*)d_in[1];
    const float* al = (const float*)d_in[2];
    float* out = (float*)d_out;
    unsigned* cb = (unsigned*)d_ws;            // 64 KB bf16 codebook

    prep_kernel<<<dim3(NK), dim3(64), 0, stream>>>(cl, cb, out);
    fused_kernel<<<dim3(512), dim3(512), 0, stream>>>(x, cb, al, out);
}

// Round 2
// 499.788 us; speedup vs baseline: 1.1303x; 1.1303x over previous
//
#include <hip/hip_runtime.h>
#include <hip/hip_bf16.h>

#define NROWS 131072
#define DIM   512
#define NK    64

typedef __attribute__((ext_vector_type(4))) float f32x4;
typedef __attribute__((ext_vector_type(8))) short s16x8;

// pack two fp32 -> one dword of two bf16 (RNE), low half = first arg
static __device__ __forceinline__ unsigned pk2(float a, float b) {
    union { __hip_bfloat162 h; unsigned u; } cv;
    cv.h = __float22bfloat162_rn(make_float2(a, b));
    return cv.u;
}

// --- Kernel 1: L2-normalize clusters (fp32) -> bf16 codebook in ws; zero loss slot.
__global__ void prep_kernel(const float* __restrict__ cl,
                            unsigned* __restrict__ cb,    // bf16[64][512] as dwords
                            float* __restrict__ loss_out) {
    const int k = blockIdx.x, t = threadIdx.x;
    const float4* rp = reinterpret_cast<const float4*>(cl + k * DIM);
    float4 f0 = rp[2 * t], f1 = rp[2 * t + 1];
    float ss = f0.x*f0.x + f0.y*f0.y + f0.z*f0.z + f0.w*f0.w
             + f1.x*f1.x + f1.y*f1.y + f1.z*f1.z + f1.w*f1.w;
#pragma unroll
    for (int m = 1; m < 64; m <<= 1) ss += __shfl_xor(ss, m, 64);
    const float rn = 1.0f / fmaxf(sqrtf(ss), 1e-12f);
    uint4 o;
    o.x = pk2(f0.x * rn, f0.y * rn);
    o.y = pk2(f0.z * rn, f0.w * rn);
    o.z = pk2(f1.x * rn, f1.y * rn);
    o.w = pk2(f1.z * rn, f1.w * rn);
    reinterpret_cast<uint4*>(cb + (size_t)k * (DIM / 2))[t] = o;
    if (k == 0 && t == 0) *loss_out = 0.0f;
}

// --- Kernel 2: fused normalize-x / MFMA GEMM / softmax / loss.
// LDS: bf16 codebook [64][512] XOR-swizzled (conflict-free b128 reads)
//      + 8 KB per-wave staging for coalesced probs stores.
__global__ __launch_bounds__(512, 4) void fused_kernel(
        const float* __restrict__ x,
        const unsigned* __restrict__ cb,
        const float* __restrict__ alphap,
        float* __restrict__ out) {                 // [0]=loss, [1..]=probs[N][64]
    __shared__ unsigned short lds[NK * DIM];       // 64 KB
    __shared__ float sbuf[8][256];                 // 8 KB: per-wave store staging

    // stage codebook: 4096 16B-units; unit c6 of row r stored at (c6 ^ (r&7))
    for (int u = threadIdx.x; u < NK * DIM / 8; u += blockDim.x) {
        const int r = u >> 6, c6 = u & 63;
        const uint4 v = reinterpret_cast<const uint4*>(cb)[u];
        *reinterpret_cast<uint4*>(&lds[r * DIM + ((c6 ^ (r & 7)) << 3)]) = v;
    }
    __syncthreads();

    const float alpha = alphap[0];
    const int lane = threadIdx.x & 63;
    const int n = lane & 15;            // A-row / B-col / C-col lane index
    const int q = lane >> 4;            // quad
    const int sw = n & 7;               // LDS unit swizzle for this lane's B rows
    const int wid = (int)(threadIdx.x >> 6);
    float* sb = sbuf[wid];
    const int gw = (int)((blockIdx.x * blockDim.x + threadIdx.x) >> 6);
    const int nw = (int)((gridDim.x * blockDim.x) >> 6);

    const unsigned short* b_base = &lds[n * DIM];

    float lossa = 0.0f;

    for (int g = gw; g < NROWS / 16; g += nw) {
        const int row0 = g << 4;
        const float4* xp4 = reinterpret_cast<const float4*>(
            x + (size_t)(row0 + n) * DIM + (q << 3));
        f32x4 a0 = {0.f,0.f,0.f,0.f}, a1 = {0.f,0.f,0.f,0.f};
        f32x4 a2 = {0.f,0.f,0.f,0.f}, a3 = {0.f,0.f,0.f,0.f};
        float ss = 0.0f;

        float4 c0 = xp4[0], c1 = xp4[1];    // 1-deep register pipeline
#pragma unroll
        for (int t = 0; t < 16; t++) {
            float4 d0, d1;
            if (t < 15) { d0 = xp4[(t + 1) * 8]; d1 = xp4[(t + 1) * 8 + 1]; }
            ss += c0.x*c0.x + c0.y*c0.y + c0.z*c0.z + c0.w*c0.w
                + c1.x*c1.x + c1.y*c1.y + c1.z*c1.z + c1.w*c1.w;
            union { s16x8 v; unsigned u[4]; } A;
            A.u[0] = pk2(c0.x, c0.y); A.u[1] = pk2(c0.z, c0.w);
            A.u[2] = pk2(c1.x, c1.y); A.u[3] = pk2(c1.z, c1.w);
            const int off = (((t << 2) | q) ^ sw) << 3;   // swizzled 16B unit
            const s16x8 b0 = *reinterpret_cast<const s16x8*>(b_base + off);
            const s16x8 b1 = *reinterpret_cast<const s16x8*>(b_base + 16 * DIM + off);
            const s16x8 b2 = *reinterpret_cast<const s16x8*>(b_base + 32 * DIM + off);
            const s16x8 b3 = *reinterpret_cast<const s16x8*>(b_base + 48 * DIM + off);
            a0 = __builtin_amdgcn_mfma_f32_16x16x32_bf16(A.v, b0, a0, 0, 0, 0);
            a1 = __builtin_amdgcn_mfma_f32_16x16x32_bf16(A.v, b1, a1, 0, 0, 0);
            a2 = __builtin_amdgcn_mfma_f32_16x16x32_bf16(A.v, b2, a2, 0, 0, 0);
            a3 = __builtin_amdgcn_mfma_f32_16x16x32_bf16(A.v, b3, a3, 0, 0, 0);
            c0 = d0; c1 = d1;
        }

        // finish ||x_row||: lanes (q,n) hold partials of row n
        ss += __shfl_xor(ss, 16, 64);
        ss += __shfl_xor(ss, 32, 64);
        const float rnorm = 1.0f / fmaxf(sqrtf(ss), 1e-12f);

#pragma unroll
        for (int r = 0; r < 4; r++) {
            // C row = q*4 + r; its rnorm lives at lanes with (lane&15) == q*4+r
            const float rn = __shfl(rnorm, (q << 2) + r, 64);
            const float i0 = a0[r] * rn, i1 = a1[r] * rn, i2 = a2[r] * rn, i3 = a3[r] * rn;
            const float z0 = i0 * alpha, z1 = i1 * alpha, z2 = i2 * alpha, z3 = i3 * alpha;
            float mx = fmaxf(fmaxf(z0, z1), fmaxf(z2, z3));
#pragma unroll
            for (int m = 1; m < 16; m <<= 1) mx = fmaxf(mx, __shfl_xor(mx, m, 64));
            const float e0 = __expf(z0 - mx), e1 = __expf(z1 - mx);
            const float e2 = __expf(z2 - mx), e3 = __expf(z3 - mx);
            float s  = e0 + e1 + e2 + e3;
            float sl = e0 * i0 + e1 * i1 + e2 * i2 + e3 * i3;   // loss uses pre-alpha ip
#pragma unroll
            for (int m = 1; m < 16; m <<= 1) {
                s  += __shfl_xor(s,  m, 64);
                sl += __shfl_xor(sl, m, 64);
            }
            const float inv = 1.0f / s;

            // stage this wave's 4 rows (1 KB) in LDS, XOR-swizzled by quad
            // (<=2-way bank aliasing = free), then store each row as one
            // wave-wide contiguous 256-B dword store.
            const int qb = q << 6, qs = q << 3;
            sb[qb + (( 0 + n) ^ qs)] = e0 * inv;
            sb[qb + ((16 + n) ^ qs)] = e1 * inv;
            sb[qb + ((32 + n) ^ qs)] = e2 * inv;
            sb[qb + ((48 + n) ^ qs)] = e3 * inv;
            float* gb = out + 1 + (size_t)(row0 + r) * NK;
#pragma unroll
            for (int j = 0; j < 4; j++) {
                const float v = sb[(j << 6) + (lane ^ (j << 3))];
                gb[(size_t)j * 4 * NK + lane] = v;      // row row0 + j*4 + r
            }
            if (n == 0) lossa += sl * inv;      // one contribution per row
        }
    }

    // wave-level loss partials live in lanes 0,16,32,48
    lossa += __shfl_xor(lossa, 16, 64);
    lossa += __shfl_xor(lossa, 32, 64);
    if (lane == 0) atomicAdd(out, -lossa * (1.0f / NROWS));
}

extern "C" void kernel_launch(void* const* d_in, const int* in_sizes, int n_in,
                              void* d_out, int out_size, void* d_ws, size_t ws_size,
                              hipStream_t stream) {
    const float* x  = (const float*)d_in[0];
    const float* cl = (const float*)d_in[1];
    const float* al = (const float*)d_in[2];
    float* out = (float*)d_out;
    unsigned* cb = (unsigned*)d_ws;            // 64 KB bf16 codebook

    prep_kernel<<<dim3(NK), dim3(64), 0, stream>>>(cl, cb, out);
    fused_kernel<<<dim3(512), dim3(512), 0, stream>>>(x, cb, al, out);
}

// Round 3
// 412.867 us; speedup vs baseline: 1.3683x; 1.2105x over previous
//
#include <hip/hip_runtime.h>
#include <hip/hip_bf16.h>

#define NROWS 131072
#define DIM   512
#define NK    64

typedef __attribute__((ext_vector_type(4))) float f32x4;
typedef __attribute__((ext_vector_type(8))) short s16x8;

// pack two fp32 -> one dword of two bf16 (RNE), low half = first arg
static __device__ __forceinline__ unsigned pk2(float a, float b) {
    union { __hip_bfloat162 h; unsigned u; } cv;
    cv.h = __float22bfloat162_rn(make_float2(a, b));
    return cv.u;
}

// --- Kernel 1: L2-normalize clusters (fp32) -> bf16 codebook in ws; zero loss slot.
__global__ void prep_kernel(const float* __restrict__ cl,
                            unsigned* __restrict__ cb,    // bf16[64][512] as dwords
                            float* __restrict__ loss_out) {
    const int k = blockIdx.x, t = threadIdx.x;
    const float4* rp = reinterpret_cast<const float4*>(cl + k * DIM);
    float4 f0 = rp[2 * t], f1 = rp[2 * t + 1];
    float ss = f0.x*f0.x + f0.y*f0.y + f0.z*f0.z + f0.w*f0.w
             + f1.x*f1.x + f1.y*f1.y + f1.z*f1.z + f1.w*f1.w;
#pragma unroll
    for (int m = 1; m < 64; m <<= 1) ss += __shfl_xor(ss, m, 64);
    const float rn = 1.0f / fmaxf(sqrtf(ss), 1e-12f);
    uint4 o;
    o.x = pk2(f0.x * rn, f0.y * rn);
    o.y = pk2(f0.z * rn, f0.w * rn);
    o.z = pk2(f1.x * rn, f1.y * rn);
    o.w = pk2(f1.z * rn, f1.w * rn);
    reinterpret_cast<uint4*>(cb + (size_t)k * (DIM / 2))[t] = o;
    if (k == 0 && t == 0) *loss_out = 0.0f;
}

// --- Kernel 2: fused normalize-x / MFMA GEMM / softmax / loss.
// LDS: 64 KB bf16 codebook (XOR-swizzled, conflict-free b128 reads)
//    + 32 KB per-wave probs staging (4 KB/wave) enabling 256-B-ALIGNED
//      shifted-window stores: out[(row0+k)*64 + lane] = sb[k*64 + lane - 1].
//      The contiguous staging supplies the +1-dword output shift across row
//      boundaries for free; only (k==0,lane==0) is foreign (masked; the
//      previous group's wave scalar-stores that dword).
// 96 KB LDS -> 1 block/CU, 8 waves/CU; 2-deep x prefetch compensates.
__global__ __launch_bounds__(512, 2) void fused_kernel(
        const float* __restrict__ x,
        const unsigned* __restrict__ cb,
        const float* __restrict__ alphap,
        float* __restrict__ out) {                 // [0]=loss, [1..]=probs[N][64]
    __shared__ unsigned short ldsb[NK * DIM];      // 64 KB codebook
    __shared__ float sbuf[8][1024];                // 32 KB store staging

    // stage codebook: 4096 16B-units; unit c6 of row r stored at (c6 ^ (r&7))
    for (int u = threadIdx.x; u < NK * DIM / 8; u += blockDim.x) {
        const int r = u >> 6, c6 = u & 63;
        const uint4 v = reinterpret_cast<const uint4*>(cb)[u];
        *reinterpret_cast<uint4*>(&ldsb[r * DIM + ((c6 ^ (r & 7)) << 3)]) = v;
    }
    __syncthreads();

    const float alpha = alphap[0];
    const int lane = threadIdx.x & 63;
    const int n = lane & 15;            // A-row / B-col / C-col lane index
    const int q = lane >> 4;            // quad
    const int sw = n & 7;               // LDS unit swizzle for this lane's B rows
    float* sb = sbuf[threadIdx.x >> 6];
    const int gw = (int)((blockIdx.x * blockDim.x + threadIdx.x) >> 6);
    const int nw = (int)((gridDim.x * blockDim.x) >> 6);

    const unsigned short* b_base = &ldsb[n * DIM];

    float lossa = 0.0f;

    for (int g = gw; g < NROWS / 16; g += nw) {
        const int row0 = g << 4;
        const float4* xp4 = reinterpret_cast<const float4*>(
            x + (size_t)(row0 + n) * DIM + (q << 3));
        f32x4 a0 = {0.f,0.f,0.f,0.f}, a1 = {0.f,0.f,0.f,0.f};
        f32x4 a2 = {0.f,0.f,0.f,0.f}, a3 = {0.f,0.f,0.f,0.f};
        float ss = 0.0f;

        // 2-deep register pipeline on x
        float4 c0 = xp4[0], c1 = xp4[1];
        float4 d0 = xp4[8], d1 = xp4[9];
#pragma unroll
        for (int t = 0; t < 16; t++) {
            float4 e0v, e1v;
            if (t < 14) { e0v = xp4[(t + 2) * 8]; e1v = xp4[(t + 2) * 8 + 1]; }
            ss += c0.x*c0.x + c0.y*c0.y + c0.z*c0.z + c0.w*c0.w
                + c1.x*c1.x + c1.y*c1.y + c1.z*c1.z + c1.w*c1.w;
            union { s16x8 v; unsigned u[4]; } A;
            A.u[0] = pk2(c0.x, c0.y); A.u[1] = pk2(c0.z, c0.w);
            A.u[2] = pk2(c1.x, c1.y); A.u[3] = pk2(c1.z, c1.w);
            const int off = (((t << 2) | q) ^ sw) << 3;   // swizzled 16B unit
            const s16x8 b0 = *reinterpret_cast<const s16x8*>(b_base + off);
            const s16x8 b1 = *reinterpret_cast<const s16x8*>(b_base + 16 * DIM + off);
            const s16x8 b2 = *reinterpret_cast<const s16x8*>(b_base + 32 * DIM + off);
            const s16x8 b3 = *reinterpret_cast<const s16x8*>(b_base + 48 * DIM + off);
            a0 = __builtin_amdgcn_mfma_f32_16x16x32_bf16(A.v, b0, a0, 0, 0, 0);
            a1 = __builtin_amdgcn_mfma_f32_16x16x32_bf16(A.v, b1, a1, 0, 0, 0);
            a2 = __builtin_amdgcn_mfma_f32_16x16x32_bf16(A.v, b2, a2, 0, 0, 0);
            a3 = __builtin_amdgcn_mfma_f32_16x16x32_bf16(A.v, b3, a3, 0, 0, 0);
            c0 = d0; c1 = d1; d0 = e0v; d1 = e1v;
        }

        // finish ||x_row||: lanes (q,n) hold partials of row n
        ss += __shfl_xor(ss, 16, 64);
        ss += __shfl_xor(ss, 32, 64);
        const float rnorm = 1.0f / fmaxf(sqrtf(ss), 1e-12f);

#pragma unroll
        for (int r = 0; r < 4; r++) {
            // C row = q*4 + r; its rnorm lives at lanes with (lane&15) == q*4+r
            const float rn = __shfl(rnorm, (q << 2) + r, 64);
            const float i0 = a0[r] * rn, i1 = a1[r] * rn, i2 = a2[r] * rn, i3 = a3[r] * rn;
            const float z0 = i0 * alpha, z1 = i1 * alpha, z2 = i2 * alpha, z3 = i3 * alpha;
            float mx = fmaxf(fmaxf(z0, z1), fmaxf(z2, z3));
#pragma unroll
            for (int m = 1; m < 16; m <<= 1) mx = fmaxf(mx, __shfl_xor(mx, m, 64));
            const float e0 = __expf(z0 - mx), e1 = __expf(z1 - mx);
            const float e2 = __expf(z2 - mx), e3 = __expf(z3 - mx);
            float s  = e0 + e1 + e2 + e3;
            float sl = e0 * i0 + e1 * i1 + e2 * i2 + e3 * i3;   // loss uses pre-alpha ip
#pragma unroll
            for (int m = 1; m < 16; m <<= 1) {
                s  += __shfl_xor(s,  m, 64);
                sl += __shfl_xor(sl, m, 64);
            }
            const float inv = 1.0f / s;
            // stage row (q*4+r) of this group's 16x64 tile, row-major contiguous
            float* sr = sb + ((q << 2) + r) * NK;
            sr[n]      = e0 * inv;
            sr[n + 16] = e1 * inv;
            sr[n + 32] = e2 * inv;
            sr[n + 48] = e3 * inv;
            if (n == 0) lossa += sl * inv;      // one contribution per row
        }

        // 16 aligned 256-B shifted-window stores:
        // out[(row0+k)*64 + lane] = element (row0+k)*64 + lane - 1 = sb[k*64+lane-1]
#pragma unroll
        for (int k = 0; k < 16; k++) {
            const int idx = k * 64 + lane - 1;
            const float v = sb[idx < 0 ? 0 : idx];
            if (k > 0 || lane > 0)
                out[(size_t)(row0 + k) * 64 + lane] = v;
        }
        // our last element goes into the next group's first aligned slot
        if (lane == 0)
            out[(size_t)(row0 + 16) * 64] = sb[1023];
    }

    // wave-level loss partials live in lanes 0,16,32,48
    lossa += __shfl_xor(lossa, 16, 64);
    lossa += __shfl_xor(lossa, 32, 64);
    if (lane == 0) atomicAdd(out, -lossa * (1.0f / NROWS));
}

extern "C" void kernel_launch(void* const* d_in, const int* in_sizes, int n_in,
                              void* d_out, int out_size, void* d_ws, size_t ws_size,
                              hipStream_t stream) {
    const float* x  = (const float*)d_in[0];
    const float* cl = (const float*)d_in[1];
    const float* al = (const float*)d_in[2];
    float* out = (float*)d_out;
    unsigned* cb = (unsigned*)d_ws;            // 64 KB bf16 codebook

    prep_kernel<<<dim3(NK), dim3(64), 0, stream>>>(cl, cb, out);
    fused_kernel<<<dim3(256), dim3(512), 0, stream>>>(x, cb, al, out);
}